// Round 8
// baseline (183.811 us; speedup 1.0000x reference)
//
#include <hip/hip_runtime.h>
#include <math.h>

#define BB 2
#define LL 2048
#define DMM 512
#define HH 8
#define DD 64
#define NUMK 40
#define NUMQ 40
#define LNEPS 1e-5f
#define LSEG 128
#define NLS 16

typedef unsigned short ushort_t;
typedef __attribute__((ext_vector_type(8))) short bf16x8;
typedef __attribute__((ext_vector_type(4))) float f32x4;

// ---- bf16 helpers (RNE) ----
__device__ inline ushort_t f2bf(float x) {
    union { float f; unsigned int u; } v; v.f = x;
    unsigned int r = v.u + 0x7fffu + ((v.u >> 16) & 1u);
    return (ushort_t)(r >> 16);
}
__device__ inline float bf2f(ushort_t h) {
    union { unsigned int u; float f; } v; v.u = ((unsigned int)h) << 16;
    return v.f;
}

// ---------------- K0: convert + transpose W -> Wt[n][k] hi/lo bf16 ----------
// X conversion is fused into proj (f32 staged to LDS, converted at frag-load).
__global__ __launch_bounds__(256) void convert_w_kernel(
    const float* __restrict__ Wq, const float* __restrict__ Wk, const float* __restrict__ Wv,
    ushort_t* __restrict__ Wht, ushort_t* __restrict__ Wlt) {
    __shared__ float tile[64][65];
    const int idx = blockIdx.x;              // 0..191
    const int z = idx >> 6, rem = idx & 63;
    const size_t plane = (size_t)DMM * DMM;
    const float* W = (z == 0) ? Wq : (z == 1) ? Wk : Wv;
    ushort_t* wht = Wht + plane * z;
    ushort_t* wlt = Wlt + plane * z;
    const int n0 = (rem & 7) * 64, k0 = (rem >> 3) * 64;
    const int t = threadIdx.x;
    const int d = t & 63, g = t >> 6;
    for (int rr = g; rr < 64; rr += 4)
        tile[rr][d] = W[(size_t)(k0 + rr) * DMM + n0 + d];
    __syncthreads();
    for (int cc = g; cc < 64; cc += 4) {
        float x = tile[d][cc];            // = W[k0+d][n0+cc]
        ushort_t hi = f2bf(x);
        ushort_t lo = f2bf(x - bf2f(hi));
        wht[(size_t)(n0 + cc) * DMM + k0 + d] = hi;
        wlt[(size_t)(n0 + cc) * DMM + k0 + d] = lo;
    }
}

// ---------------- K1: split-bf16 MFMA projection GEMM (3-term) --------------
// 128x128 tile, 4 waves x 64x64. A staged as RAW F32 via global_load_lds
// (same bytes/instr count as hi+lo bf16), converted to hi/lo bf16 in
// registers at fragment-load (same f2bf on same values -> bit-identical).
// Deletes the 100 MB convert-X round trip. B = pre-converted W (tiny).
__device__ inline void stage_oneB(const ushort_t* __restrict__ g, ushort_t* lbuf,
                                  int r0, int lane, int k0) {
    const int r = r0 + (lane >> 3);
    const int c = (lane & 7) ^ (r & 7);
    const ushort_t* gp = g + (size_t)r * DMM + k0 + c * 8;
    __builtin_amdgcn_global_load_lds(
        (const __attribute__((address_space(1))) unsigned int*)gp,
        (__attribute__((address_space(3))) unsigned int*)(lbuf + (size_t)r0 * 64),
        16, 0, 0);
}
__device__ inline bf16x8 frag_ld(const ushort_t* buf, int row, int c) {
    const int idx = row * 8 + (c ^ (row & 7));
    return *(const bf16x8*)(buf + idx * 8);
}
// A fragment from f32 LDS tile (16 slots of 16B per 256B row, XOR r&15):
__device__ inline void frag_ld_cvt(const float* buf, int row, int cc,
                                   bf16x8& fh, bf16x8& fl) {
    const int s0 = (2 * cc)     ^ (row & 15);
    const int s1 = (2 * cc + 1) ^ (row & 15);
    const float4 x0 = *(const float4*)(buf + row * 64 + s0 * 4);
    const float4 x1 = *(const float4*)(buf + row * 64 + s1 * 4);
    const float xs[8] = {x0.x, x0.y, x0.z, x0.w, x1.x, x1.y, x1.z, x1.w};
#pragma unroll
    for (int j = 0; j < 8; ++j) {
        const ushort_t h = f2bf(xs[j]);
        fh[j] = (short)h;
        fl[j] = (short)f2bf(xs[j] - bf2f(h));
    }
}

__global__ __launch_bounds__(256, 2) void proj_mfma_kernel(
    const float* __restrict__ Xq, const float* __restrict__ Xk, const float* __restrict__ Xv,
    const ushort_t* __restrict__ Wht, const ushort_t* __restrict__ Wlt,
    const float* __restrict__ bq, const float* __restrict__ bk, const float* __restrict__ bv,
    float* __restrict__ Oq, float* __restrict__ Ok, float* __restrict__ Ov) {
    // flat grid of 384; xcd = orig%8 gets 48 consecutive work-chunks
    // chunk c = z*128 + mb*4 + jb  (j innermost -> A-panel L2 reuse per XCD)
    const int orig = blockIdx.x;
    const int c = (orig & 7) * 48 + (orig >> 3);
    const int jb = c & 3, mb = (c >> 2) & 31, z = c >> 7;

    const size_t wplane = (size_t)DMM * DMM;
    const float* X32 = (z == 0) ? Xq : (z == 1) ? Xk : Xv;
    const ushort_t* bh_g = Wht + wplane * z;
    const ushort_t* bl_g = Wlt + wplane * z;
    const float* bias = (z == 0) ? bq : (z == 1) ? bk : bv;
    float* Out = (z == 0) ? Oq : (z == 1) ? Ok : Ov;

    __shared__ __align__(16) float    bufA[128 * 64];       // 32 KB (f32)
    __shared__ __align__(16) ushort_t bufBh[128 * 64];      // 16 KB
    __shared__ __align__(16) ushort_t bufBl[128 * 64];      // 16 KB

    const int t = threadIdx.x;
    const int lane = t & 63, w = t >> 6;
    const int wm = (w & 1) * 64, wn = (w >> 1) * 64;
    const int m0 = mb * 128, j0 = jb * 128;

    const float* A32 = X32 + (size_t)m0 * DMM;
    const ushort_t* B_h = bh_g + (size_t)j0 * DMM;
    const ushort_t* B_l = bl_g + (size_t)j0 * DMM;

    f32x4 acc[4][4];
#pragma unroll
    for (int i = 0; i < 4; ++i)
#pragma unroll
        for (int j = 0; j < 4; ++j) acc[i][j] = (f32x4){0.f, 0.f, 0.f, 0.f};

    for (int ch = 0; ch < 8; ++ch) {
        const int k0 = ch * 64;
        // ---- stage A (f32): 8 instr/wave, 4 rows each; 16-slot XOR swizzle
#pragma unroll
        for (int i = 0; i < 8; ++i) {
            const int r0 = (w * 8 + i) * 4;              // wave-uniform
            const int r = r0 + (lane >> 4);
            const int cg = (lane & 15) ^ (r & 15);
            const float* gp = A32 + (size_t)r * DMM + k0 + cg * 4;
            __builtin_amdgcn_global_load_lds(
                (const __attribute__((address_space(1))) unsigned int*)gp,
                (__attribute__((address_space(3))) unsigned int*)(bufA + (size_t)r0 * 64),
                16, 0, 0);
        }
        // ---- stage B (bf16 hi/lo)
#pragma unroll
        for (int i = 0; i < 4; ++i) {
            const int r0 = (w * 4 + i) * 8;
            stage_oneB(B_h, bufBh, r0, lane, k0);
            stage_oneB(B_l, bufBl, r0, lane, k0);
        }
        __syncthreads();
#pragma unroll
        for (int ks = 0; ks < 2; ++ks) {
            const int cc = ks * 4 + (lane >> 4);
            bf16x8 fah[4], fal[4];
#pragma unroll
            for (int tm = 0; tm < 4; ++tm) {
                const int row = wm + tm * 16 + (lane & 15);
                frag_ld_cvt(bufA, row, cc, fah[tm], fal[tm]);
            }
#pragma unroll
            for (int tn = 0; tn < 4; ++tn) {
                const int rowb = wn + tn * 16 + (lane & 15);
                const bf16x8 fbh = frag_ld(bufBh, rowb, cc);
                const bf16x8 fbl = frag_ld(bufBl, rowb, cc);
#pragma unroll
                for (int tm = 0; tm < 4; ++tm) {
                    acc[tm][tn] = __builtin_amdgcn_mfma_f32_16x16x32_bf16(fah[tm], fbh, acc[tm][tn], 0, 0, 0);
                    acc[tm][tn] = __builtin_amdgcn_mfma_f32_16x16x32_bf16(fal[tm], fbh, acc[tm][tn], 0, 0, 0);
                    acc[tm][tn] = __builtin_amdgcn_mfma_f32_16x16x32_bf16(fah[tm], fbl, acc[tm][tn], 0, 0, 0);
                }
            }
        }
        __syncthreads();
    }

#pragma unroll
    for (int tn = 0; tn < 4; ++tn) {
        const int gn = j0 + wn + tn * 16 + (lane & 15);
        const float bvv = bias[gn];
        const int h = gn >> 6, d = gn & 63;
#pragma unroll
        for (int tm = 0; tm < 4; ++tm) {
#pragma unroll
            for (int reg = 0; reg < 4; ++reg) {
                const int gm = m0 + wm + tm * 16 + (lane >> 4) * 4 + reg;
                const int b = gm >> 11, l = gm & (LL - 1);
                Out[(((size_t)(b * HH + h)) * LL + l) * DD + d] = acc[tm][tn][reg] + bvv;
            }
        }
    }
}

// ---------------- K_C: measure + vmean1 in one launch -----------------------
// measure blocks XCD-swizzled: c = (orig%8)*256 + orig/8 (2048%8==0, bijective)
// -> each XCD owns 2 bh -> kp2 slices stay L2-resident per XCD.
__global__ __launch_bounds__(256) void measure_vmean_kernel(
    const float* __restrict__ qp2, const float* __restrict__ kp2,
    const float* __restrict__ vp2, const int* __restrict__ rnd,
    float* __restrict__ measure, float* __restrict__ partial) {
    __shared__ float pv[256];
    const int bx = blockIdx.x;
    const int t = threadIdx.x;
    if (bx < 2048) {
        const int c = (bx & 7) * 256 + (bx >> 3);
        const int lane = t & 63;
        const int wv = t >> 6;
        const int g = lane >> 4;
        const int dq = (lane & 15) * 4;
        const int bh = c >> 7;
        const int i = (c & 127) * 16 + wv * 4 + g;
        const float4 qv = *(const float4*)(qp2 + ((size_t)bh * LL + i) * DD + dq);
        const float* kbase = kp2 + (size_t)bh * LL * DD;
        const int* rp = rnd + i * NUMK;
        float mx = -INFINITY, sm = 0.f;
#pragma unroll 8
        for (int j = 0; j < NUMK; ++j) {
            const int row = rp[j];
            const float4 kv = *(const float4*)(kbase + (size_t)row * DD + dq);
            float p = kv.x * qv.x;
            p = fmaf(kv.y, qv.y, p); p = fmaf(kv.z, qv.z, p); p = fmaf(kv.w, qv.w, p);
            p += __shfl_xor(p, 1, 64);
            p += __shfl_xor(p, 2, 64);
            p += __shfl_xor(p, 4, 64);
            p += __shfl_xor(p, 8, 64);
            mx = fmaxf(mx, p);
            sm += p;
        }
        if ((lane & 15) == 0) measure[(size_t)bh * LL + i] = mx - sm * (1.0f / LL);
    } else {
        const int idx = bx - 2048;
        const int chunk = idx & 31;
        const int bh = idx >> 5;
        const int d = t & 63, g = t >> 6;
        const int l0 = chunk * 64;
        float acc = 0.f;
        for (int l = l0 + g; l < l0 + 64; l += 4)
            acc += vp2[((size_t)bh * LL + l) * DD + d];
        pv[t] = acc;
        __syncthreads();
        if (t < 64)
            partial[(size_t)idx * 64 + t] = pv[t] + pv[64 + t] + pv[128 + t] + pv[192 + t];
    }
}

// ---------------- K3: top-40 radix + vmean2 ---------------------------------
// Round-0 histogram via wave ballot aggregation; bin selection via
// single-wave shfl suffix-scan.
__global__ __launch_bounds__(256) void topk_kernel(const float* __restrict__ measure,
                                                   const float* __restrict__ partial,
                                                   int* __restrict__ q_idx,
                                                   int* __restrict__ sel_pos,
                                                   float* __restrict__ v_mean) {
    __shared__ unsigned int keys[LL];      // 8 KB
    __shared__ int hist[256];
    __shared__ unsigned int prefix_sh;
    __shared__ int need_sh;
    __shared__ unsigned int cval[256];
    __shared__ int cidx[256];
    __shared__ int cnt;
    const int t = threadIdx.x;
    const int lane = t & 63;
    const int bh = blockIdx.x;
    for (int i = t; i < LL; i += 256) {
        const float f = measure[(size_t)bh * LL + i];
        unsigned int u = __float_as_uint(f);
        keys[i] = (u & 0x80000000u) ? ~u : (u | 0x80000000u);
        sel_pos[(size_t)bh * LL + i] = -1;
    }
    // folded vmean2: independent of topk state
    if (t < 64) {
        float s = 0.f;
        for (int c = 0; c < 32; ++c)
            s += partial[((size_t)bh * 32 + c) * 64 + t];
        v_mean[bh * 64 + t] = s * (1.0f / LL);
    }
    if (t == 0) { prefix_sh = 0u; need_sh = NUMQ; cnt = 0; }
    __syncthreads();

    for (int round = 0; round < 4; ++round) {
        const int shift = 24 - round * 8;
        hist[t] = 0;
        __syncthreads();
        const unsigned int pref = prefix_sh;
        if (round == 0) {
            // leader-election aggregation (all lanes active; LL % 256 == 0)
            for (int i = t; i < LL; i += 256) {
                const int b = (int)(keys[i] >> 24);
                unsigned long long rem = ~0ull;
                while (rem) {
                    const int leader = __ffsll((long long)rem) - 1;
                    const int b0 = __shfl(b, leader, 64);
                    const unsigned long long same = __ballot(b == b0) & rem;
                    if (lane == leader) atomicAdd(&hist[b0], (int)__popcll(same));
                    rem &= ~same;
                }
            }
        } else {
            const unsigned int mask = 0xFFFFFFFFu << (shift + 8);
            for (int i = t; i < LL; i += 256) {
                const unsigned int key = keys[i];
                if ((key & mask) == pref)
                    atomicAdd(&hist[(key >> shift) & 0xFF], 1);
            }
        }
        __syncthreads();
        // single-wave suffix-scan bin selection (t < 64 -> wave 0)
        if (t < 64) {
            const int b0 = hist[4 * t + 0], b1 = hist[4 * t + 1];
            const int b2 = hist[4 * t + 2], b3 = hist[4 * t + 3];
            const int loc = b0 + b1 + b2 + b3;
            int suf = loc;
#pragma unroll
            for (int off = 1; off < 64; off <<= 1) {
                const int other = __shfl_down(suf, off, 64);
                if (lane + off < 64) suf += other;
            }
            // suf = suffix(4t) inclusive
            const int need = need_sh;
            int s[5];
            s[0] = suf;
            s[1] = suf - b0;
            s[2] = suf - b0 - b1;
            s[3] = suf - b0 - b1 - b2;
            s[4] = suf - loc;
#pragma unroll
            for (int kk = 0; kk < 4; ++kk) {
                if (s[kk] >= need && s[kk + 1] < need) {
                    need_sh = need - s[kk + 1];
                    prefix_sh = pref | ((unsigned int)(4 * t + kk) << shift);
                }
            }
        }
        __syncthreads();
    }
    const unsigned int K40 = prefix_sh;

    for (int i = t; i < LL; i += 256) {
        if (keys[i] >= K40) {
            int p = atomicAdd(&cnt, 1);
            if (p < 256) { cval[p] = keys[i]; cidx[p] = i; }
        }
    }
    __syncthreads();
    int M = cnt; if (M > 256) M = 256;
    for (int i = t; i < M; i += 256) {
        const unsigned int ki = cval[i];
        const int ii = cidx[i];
        int r = 0;
        for (int j = 0; j < M; ++j) {
            const unsigned int kj = cval[j];
            r += (kj > ki || (kj == ki && cidx[j] < ii)) ? 1 : 0;
        }
        if (r < NUMQ) {
            q_idx[bh * NUMQ + r] = ii;
            sel_pos[(size_t)bh * LL + ii] = r;
        }
    }
}

// ---------------- K4a: attn partial — all 40 queries per block --------------
// One block per (bh, 128-key segment). K staged, barrier, THEN V-stage issued
// so it flies under QK^T (T14 issue-early); V drained by the pre-PV barrier.
__global__ __launch_bounds__(256) void attn_part_kernel(
    const float* __restrict__ qp2, const float* __restrict__ kp2,
    const float* __restrict__ vp2, const int* __restrict__ q_idx,
    float* __restrict__ attn_out, float* __restrict__ part_m,
    float* __restrict__ part_s, float* __restrict__ part_pv) {
    __shared__ __align__(16) float Qs[NUMQ][68];        // ~10.9 KB, q * 0.125
    __shared__ __align__(16) float Ks[LSEG * 64];       // 32 KB, XOR-swizzled
    __shared__ __align__(16) float Vs[LSEG * 64];       // 32 KB, XOR-swizzled
    __shared__ __align__(16) float Ss[NUMQ][136];       // ~21.8 KB, exp'd P
    const int t = threadIdx.x;
    const int lane = t & 63, w = t >> 6;
    // flat 256-block grid; c = (orig%8)*32 + orig/8 (256%8==0, bijective)
    const int orig = blockIdx.x;
    const int cc_ = (orig & 7) * 32 + (orig >> 3);
    const int bh = cc_ >> 4;
    const int ls = cc_ & 15;
    const int l0 = ls * LSEG;

    // ---- load Q (scaled by D^-1/2 = 0.125) ----
    for (int idx = t; idx < NUMQ * 16; idx += 256) {
        const int r = idx >> 4, c4 = idx & 15;
        const int qi = q_idx[bh * NUMQ + r];
        float4 v = *(const float4*)(qp2 + ((size_t)bh * LL + qi) * DD + c4 * 4);
        Qs[r][c4 * 4 + 0] = v.x * 0.125f;
        Qs[r][c4 * 4 + 1] = v.y * 0.125f;
        Qs[r][c4 * 4 + 2] = v.z * 0.125f;
        Qs[r][c4 * 4 + 3] = v.w * 0.125f;
    }

    // ---- stage K segment ----
    const float* kseg = kp2 + ((size_t)bh * LL + l0) * DD;
    const float* vseg = vp2 + ((size_t)bh * LL + l0) * DD;
#pragma unroll
    for (int i = 0; i < 8; ++i) {
        const int r0 = (w * 8 + i) * 4;                 // wave-uniform
        const int r = r0 + (lane >> 4);
        const int cg = (lane & 15) ^ (r & 15);
        __builtin_amdgcn_global_load_lds(
            (const __attribute__((address_space(1))) unsigned int*)(kseg + (size_t)r * DD + cg * 4),
            (__attribute__((address_space(3))) unsigned int*)(Ks + r0 * 64), 16, 0, 0);
    }
    __syncthreads();   // Q writes + K gloads drained

    // ---- issue V staging now: flies under QK^T, drained by next barrier ----
#pragma unroll
    for (int i = 0; i < 8; ++i) {
        const int r0 = (w * 8 + i) * 4;                 // wave-uniform
        const int r = r0 + (lane >> 4);
        const int cg = (lane & 15) ^ (r & 15);
        __builtin_amdgcn_global_load_lds(
            (const __attribute__((address_space(1))) unsigned int*)(vseg + (size_t)r * DD + cg * 4),
            (__attribute__((address_space(3))) unsigned int*)(Vs + r0 * 64), 16, 0, 0);
    }

    // ---- QK^T: acc[5][4] ----
    const int qt = t >> 5;          // 0..7  (32-thread group per q-residue)
    const int jt = t & 31;          // 0..31
    float acc[5][4];
#pragma unroll
    for (int i = 0; i < 5; ++i)
#pragma unroll
        for (int jj = 0; jj < 4; ++jj) acc[i][jj] = 0.f;

    for (int c4 = 0; c4 < 16; ++c4) {
        float4 q4[5];
#pragma unroll
        for (int i = 0; i < 5; ++i)
            q4[i] = *(const float4*)&Qs[qt + 8 * i][c4 * 4];    // broadcast
#pragma unroll
        for (int jj = 0; jj < 4; ++jj) {
            const int r = jt + 32 * jj;
            const float4 k4 = *(const float4*)&Ks[r * 64 + ((c4 ^ (r & 15)) * 4)];
#pragma unroll
            for (int i = 0; i < 5; ++i) {
                acc[i][jj] = fmaf(q4[i].x, k4.x, acc[i][jj]);
                acc[i][jj] = fmaf(q4[i].y, k4.y, acc[i][jj]);
                acc[i][jj] = fmaf(q4[i].z, k4.z, acc[i][jj]);
                acc[i][jj] = fmaf(q4[i].w, k4.w, acc[i][jj]);
            }
        }
    }

    // ---- per-row partial softmax (max & sum over this 128-seg) ----
#pragma unroll
    for (int i = 0; i < 5; ++i) {
        const int r = qt + 8 * i;
        float m = fmaxf(fmaxf(acc[i][0], acc[i][1]), fmaxf(acc[i][2], acc[i][3]));
        m = fmaxf(m, __shfl_xor(m, 16, 64));
        m = fmaxf(m, __shfl_xor(m, 8, 64));
        m = fmaxf(m, __shfl_xor(m, 4, 64));
        m = fmaxf(m, __shfl_xor(m, 2, 64));
        m = fmaxf(m, __shfl_xor(m, 1, 64));
        float p0 = __expf(acc[i][0] - m), p1 = __expf(acc[i][1] - m);
        float p2 = __expf(acc[i][2] - m), p3 = __expf(acc[i][3] - m);
        Ss[r][jt]      = p0;
        Ss[r][jt + 32] = p1;
        Ss[r][jt + 64] = p2;
        Ss[r][jt + 96] = p3;
        float s = p0 + p1 + p2 + p3;
        s += __shfl_xor(s, 16, 64);
        s += __shfl_xor(s, 8, 64);
        s += __shfl_xor(s, 4, 64);
        s += __shfl_xor(s, 2, 64);
        s += __shfl_xor(s, 1, 64);
        if (jt == 0) {
            const int row = bh * NUMQ + r;
            part_m[row * NLS + ls] = m;
            part_s[row * NLS + ls] = s;
        }
    }
    __syncthreads();   // drains V gloads + Ss writes

    // ---- coalesced write of unnormalized P to attn_out ----
    for (int idx = t; idx < NUMQ * 32; idx += 256) {
        const int r = idx >> 5, c4 = idx & 31;
        const float4 v = *(const float4*)&Ss[r][c4 * 4];
        *(float4*)(attn_out + (size_t)(bh * NUMQ + r) * LL + l0 + c4 * 4) = v;
    }

    // ---- PV: thread tile 5q x 2d; P read as float4 per 4-j ----
    const int dt = t & 31;
    float o[5][2];
#pragma unroll
    for (int i = 0; i < 5; ++i) { o[i][0] = 0.f; o[i][1] = 0.f; }
#pragma unroll 2
    for (int j0_ = 0; j0_ < LSEG; j0_ += 4) {
        float4 p4[5];
#pragma unroll
        for (int i = 0; i < 5; ++i)
            p4[i] = *(const float4*)&Ss[qt + 8 * i][j0_];       // broadcast b128
#pragma unroll
        for (int jj = 0; jj < 4; ++jj) {
            const int j = j0_ + jj;
            const int pg = (dt >> 1) ^ (j & 15);
            const float* vr = &Vs[j * 64 + pg * 4 + (dt & 1) * 2];
            const float v0 = vr[0], v1 = vr[1];
#pragma unroll
            for (int i = 0; i < 5; ++i) {
                const float p = ((const float*)&p4[i])[jj];     // jj compile-time
                o[i][0] = fmaf(p, v0, o[i][0]);
                o[i][1] = fmaf(p, v1, o[i][1]);
            }
        }
    }
#pragma unroll
    for (int i = 0; i < 5; ++i) {
        const int row = bh * NUMQ + qt + 8 * i;
        float* pp = part_pv + ((size_t)row * NLS + ls) * DD + dt * 2;
        pp[0] = o[i][0];
        pp[1] = o[i][1];
    }
}

// ---------------- K_F: final (token LN) + attn rescale, one launch ----------
__global__ __launch_bounds__(512) void final_all_kernel(
    const float* __restrict__ q_in, const int* __restrict__ sel_pos,
    const float* __restrict__ part_m, const float* __restrict__ part_s,
    const float* __restrict__ part_pv, const float* __restrict__ v_mean,
    const float* __restrict__ gamma, const float* __restrict__ beta,
    float* __restrict__ attn_out, float* __restrict__ yout) {
    __shared__ float wred[8];
    const int bx = blockIdx.x;
    const int j = threadIdx.x;
    if (bx >= BB * LL) {
        // ---- attn_out row rescale: 512 threads x one float4 = 2048 cols ----
        const int row = bx - BB * LL;        // bh*NUMQ + q
        float M = -INFINITY;
#pragma unroll
        for (int i = 0; i < NLS; ++i) M = fmaxf(M, part_m[row * NLS + i]);
        float T = 0.f;
#pragma unroll
        for (int i = 0; i < NLS; ++i)
            T += part_s[row * NLS + i] * __expf(part_m[row * NLS + i] - M);
        const float inv = 1.0f / T;
        const int s0 = j >> 5;               // col 4j -> segment (4j)>>7
        const float g = __expf(part_m[row * NLS + s0] - M) * inv;
        float* arow = attn_out + (size_t)row * LL;
        float4 v = *(const float4*)&arow[4 * j];
        v.x *= g; v.y *= g; v.z *= g; v.w *= g;
        *(float4*)&arow[4 * j] = v;
        return;
    }
    const int lane = j & 63, wv = j >> 6;
    const int tok = bx;                      // b*L + l
    const int b = tok >> 11;
    const int l = tok & (LL - 1);
    const int h = wv, d = lane;
    const int bh = b * HH + h;
    const int p = sel_pos[(size_t)bh * LL + l];
    float val;
    if (p >= 0) {
        const int row = bh * NUMQ + p;
        float M = -INFINITY;
#pragma unroll
        for (int i = 0; i < NLS; ++i) M = fmaxf(M, part_m[row * NLS + i]);
        float T = 0.f, s = 0.f;
#pragma unroll
        for (int i = 0; i < NLS; ++i) {
            const float e = __expf(part_m[row * NLS + i] - M);
            T += part_s[row * NLS + i] * e;
            s += part_pv[((size_t)row * NLS + i) * DD + d] * e;
        }
        val = s * (1.0f / T);
    } else {
        val = v_mean[bh * DD + d];
    }
    float y = val + q_in[(size_t)tok * DMM + j];
    float s = y;
#pragma unroll
    for (int off = 32; off > 0; off >>= 1) s += __shfl_xor(s, off, 64);
    if (lane == 0) wred[wv] = s;
    __syncthreads();
    float tot = 0.f;
#pragma unroll
    for (int u = 0; u < 8; ++u) tot += wred[u];
    float mu = tot * (1.0f / DMM);
    __syncthreads();
    float dv = y - mu;
    float s2 = dv * dv;
#pragma unroll
    for (int off = 32; off > 0; off >>= 1) s2 += __shfl_xor(s2, off, 64);
    if (lane == 0) wred[wv] = s2;
    __syncthreads();
    float tot2 = 0.f;
#pragma unroll
    for (int u = 0; u < 8; ++u) tot2 += wred[u];
    float var = tot2 * (1.0f / DMM);
    float yn = dv * rsqrtf(var + LNEPS) * gamma[j] + beta[j];
    yout[(size_t)tok * DMM + j] = yn;
}

extern "C" void kernel_launch(void* const* d_in, const int* in_sizes, int n_in,
                              void* d_out, int out_size, void* d_ws, size_t ws_size,
                              hipStream_t stream) {
    const float* q     = (const float*)d_in[0];
    const float* k     = (const float*)d_in[1];
    const float* v     = (const float*)d_in[2];
    const float* Wq    = (const float*)d_in[3];
    const float* bq    = (const float*)d_in[4];
    const float* Wk    = (const float*)d_in[5];
    const float* bk    = (const float*)d_in[6];
    const float* Wv    = (const float*)d_in[7];
    const float* bv    = (const float*)d_in[8];
    const float* gamma = (const float*)d_in[9];
    const float* beta  = (const float*)d_in[10];
    const int*   rnd   = (const int*)d_in[11];

    float* ws = (float*)d_ws;
    const size_t proj_sz = (size_t)BB * HH * LL * DD;      // = B*L*DM elements
    float* qp2     = ws;
    float* kp2     = qp2 + proj_sz;
    float* vp2     = kp2 + proj_sz;
    float* measure = vp2 + proj_sz;                        // B*H*L
    float* out_sel = measure + (size_t)BB * HH * LL;       // (unused slot)
    float* v_mean  = out_sel + (size_t)BB * HH * NUMQ * DD;// B*H*D
    float* partial = v_mean + (size_t)BB * HH * DD;        // B*H*32*64
    float* part_m  = partial + (size_t)BB * HH * 32 * 64;  // 640*NLS
    float* part_s  = part_m + (size_t)BB * HH * NUMQ * NLS;
    float* part_pv = part_s + (size_t)BB * HH * NUMQ * NLS;// 640*NLS*64
    int*   q_idx   = (int*)(part_pv + (size_t)BB * HH * NUMQ * NLS * DD);
    int*   sel_pos = q_idx + BB * HH * NUMQ;               // B*H*L
    ushort_t* Wht = (ushort_t*)(sel_pos + BB * HH * LL);
    ushort_t* Wlt = Wht + 3 * (size_t)DMM * DMM;

    float* yn_out   = (float*)d_out;
    float* attn_out = yn_out + (size_t)BB * LL * DMM;

    convert_w_kernel<<<192, 256, 0, stream>>>(Wq, Wk, Wv, Wht, Wlt);
    proj_mfma_kernel<<<dim3(3 * (BB * LL / 128) * (DMM / 128), 1, 1), 256, 0, stream>>>(
        q, k, v, Wht, Wlt, bq, bk, bv, qp2, kp2, vp2);
    measure_vmean_kernel<<<2048 + 512, 256, 0, stream>>>(qp2, kp2, vp2, rnd, measure, partial);
    topk_kernel<<<BB * HH, 256, 0, stream>>>(measure, partial, q_idx, sel_pos, v_mean);
    attn_part_kernel<<<BB * HH * NLS, 256, 0, stream>>>(
        qp2, kp2, vp2, q_idx, attn_out, part_m, part_s, part_pv);
    final_all_kernel<<<BB * LL + BB * HH * NUMQ, 512, 0, stream>>>(
        q, sel_pos, part_m, part_s, part_pv, v_mean, gamma, beta, attn_out, yn_out);
}

// Round 9
// 175.316 us; speedup vs baseline: 1.0485x; 1.0485x over previous
//
#include <hip/hip_runtime.h>
#include <math.h>

#define BB 2
#define LL 2048
#define DMM 512
#define HH 8
#define DD 64
#define NUMK 40
#define NUMQ 40
#define LNEPS 1e-5f
#define LSEG 128
#define NLS 16

typedef unsigned short ushort_t;
typedef __attribute__((ext_vector_type(8))) short bf16x8;
typedef __attribute__((ext_vector_type(4))) float f32x4;

// ---- bf16 helpers (RNE) ----
__device__ inline ushort_t f2bf(float x) {
    union { float f; unsigned int u; } v; v.f = x;
    unsigned int r = v.u + 0x7fffu + ((v.u >> 16) & 1u);
    return (ushort_t)(r >> 16);
}
__device__ inline float bf2f(ushort_t h) {
    union { unsigned int u; float f; } v; v.u = ((unsigned int)h) << 16;
    return v.f;
}

// ---------------- K_A: convert X (q,k,v) + W -> hi/lo bf16 ------------------
// blocks 0..3071: X path (1024 per tensor). blocks 3072..3263: W path.
// Standalone conversion is measured-optimal: R6 (reg-staged fuse) -12us,
// R8 (frag-load fuse) -7us vs this structure.
__global__ __launch_bounds__(256) void convert_all_kernel(
    const float* __restrict__ q, const float* __restrict__ k, const float* __restrict__ v,
    const float* __restrict__ Wq, const float* __restrict__ Wk, const float* __restrict__ Wv,
    ushort_t* __restrict__ Xh, ushort_t* __restrict__ Xl,
    ushort_t* __restrict__ Wht, ushort_t* __restrict__ Wlt) {
    __shared__ float tile[64][65];
    const int bx = blockIdx.x;
    const int t = threadIdx.x;
    if (bx < 3072) {
        const int y = bx >> 10, x = bx & 1023;
        const size_t plane = (size_t)BB * LL * DMM;
        const float* X = (y == 0) ? q : (y == 1) ? k : v;
        ushort_t* xh = Xh + plane * y;
        ushort_t* xl = Xl + plane * y;
        const size_t base = ((size_t)x * 256 + t) * 8;
        float4 a = *(const float4*)(X + base);
        float4 b = *(const float4*)(X + base + 4);
        float xs[8] = {a.x, a.y, a.z, a.w, b.x, b.y, b.z, b.w};
        unsigned int hp[4], lp[4];
#pragma unroll
        for (int j = 0; j < 4; ++j) {
            ushort_t h0 = f2bf(xs[2 * j]),     h1 = f2bf(xs[2 * j + 1]);
            ushort_t l0 = f2bf(xs[2 * j] - bf2f(h0));
            ushort_t l1 = f2bf(xs[2 * j + 1] - bf2f(h1));
            hp[j] = (unsigned int)h0 | ((unsigned int)h1 << 16);
            lp[j] = (unsigned int)l0 | ((unsigned int)l1 << 16);
        }
        *(uint4*)(xh + base) = make_uint4(hp[0], hp[1], hp[2], hp[3]);
        *(uint4*)(xl + base) = make_uint4(lp[0], lp[1], lp[2], lp[3]);
    } else {
        const int idx = bx - 3072;               // 0..191
        const int z = idx >> 6, rem = idx & 63;
        const size_t plane = (size_t)DMM * DMM;
        const float* W = (z == 0) ? Wq : (z == 1) ? Wk : Wv;
        ushort_t* wht = Wht + plane * z;
        ushort_t* wlt = Wlt + plane * z;
        const int n0 = (rem & 7) * 64, k0 = (rem >> 3) * 64;
        const int d = t & 63, g = t >> 6;
        for (int rr = g; rr < 64; rr += 4)
            tile[rr][d] = W[(size_t)(k0 + rr) * DMM + n0 + d];
        __syncthreads();
        for (int cc = g; cc < 64; cc += 4) {
            float x = tile[d][cc];            // = W[k0+d][n0+cc]
            ushort_t hi = f2bf(x);
            ushort_t lo = f2bf(x - bf2f(hi));
            wht[(size_t)(n0 + cc) * DMM + k0 + d] = hi;
            wlt[(size_t)(n0 + cc) * DMM + k0 + d] = lo;
        }
    }
}

// ---------------- K1: split-bf16 MFMA projection GEMM (3-term) --------------
// 128x128 tile, 4 waves x 64x64. global_load_lds staging of pre-converted
// hi/lo bf16 (R5/R7-proven structure, 176.5us total).
__device__ inline void stage_one(const ushort_t* __restrict__ g, ushort_t* lbuf,
                                 int r0, int lane, int k0) {
    const int r = r0 + (lane >> 3);
    const int c = (lane & 7) ^ (r & 7);
    const ushort_t* gp = g + (size_t)r * DMM + k0 + c * 8;
    __builtin_amdgcn_global_load_lds(
        (const __attribute__((address_space(1))) unsigned int*)gp,
        (__attribute__((address_space(3))) unsigned int*)(lbuf + (size_t)r0 * 64),
        16, 0, 0);
}
__device__ inline bf16x8 frag_ld(const ushort_t* buf, int row, int c) {
    const int idx = row * 8 + (c ^ (row & 7));
    return *(const bf16x8*)(buf + idx * 8);
}

__global__ __launch_bounds__(256, 2) void proj_mfma_kernel(
    const ushort_t* __restrict__ Xh, const ushort_t* __restrict__ Xl,
    const ushort_t* __restrict__ Wht, const ushort_t* __restrict__ Wlt,
    const float* __restrict__ bq, const float* __restrict__ bk, const float* __restrict__ bv,
    float* __restrict__ Oq, float* __restrict__ Ok, float* __restrict__ Ov) {
    // flat grid of 384; xcd = orig%8 gets 48 consecutive work-chunks
    // chunk c = z*128 + mb*4 + jb  (j innermost -> A-panel L2 reuse per XCD)
    const int orig = blockIdx.x;
    const int c = (orig & 7) * 48 + (orig >> 3);
    const int jb = c & 3, mb = (c >> 2) & 31, z = c >> 7;

    const size_t xplane = (size_t)BB * LL * DMM;
    const size_t wplane = (size_t)DMM * DMM;
    const ushort_t* ah_g = Xh + xplane * z;
    const ushort_t* al_g = Xl + xplane * z;
    const ushort_t* bh_g = Wht + wplane * z;
    const ushort_t* bl_g = Wlt + wplane * z;
    const float* bias = (z == 0) ? bq : (z == 1) ? bk : bv;
    float* Out = (z == 0) ? Oq : (z == 1) ? Ok : Ov;

    __shared__ __align__(16) ushort_t bufAh[128 * 64];
    __shared__ __align__(16) ushort_t bufAl[128 * 64];
    __shared__ __align__(16) ushort_t bufBh[128 * 64];
    __shared__ __align__(16) ushort_t bufBl[128 * 64];

    const int t = threadIdx.x;
    const int lane = t & 63, w = t >> 6;
    const int wm = (w & 1) * 64, wn = (w >> 1) * 64;
    const int m0 = mb * 128, j0 = jb * 128;

    const ushort_t* A_h = ah_g + (size_t)m0 * DMM;
    const ushort_t* A_l = al_g + (size_t)m0 * DMM;
    const ushort_t* B_h = bh_g + (size_t)j0 * DMM;
    const ushort_t* B_l = bl_g + (size_t)j0 * DMM;

    f32x4 acc[4][4];
#pragma unroll
    for (int i = 0; i < 4; ++i)
#pragma unroll
        for (int j = 0; j < 4; ++j) acc[i][j] = (f32x4){0.f, 0.f, 0.f, 0.f};

    for (int ch = 0; ch < 8; ++ch) {
        const int k0 = ch * 64;
#pragma unroll
        for (int i = 0; i < 4; ++i) {
            const int r0 = (w * 4 + i) * 8;
            stage_one(A_h, bufAh, r0, lane, k0);
            stage_one(A_l, bufAl, r0, lane, k0);
            stage_one(B_h, bufBh, r0, lane, k0);
            stage_one(B_l, bufBl, r0, lane, k0);
        }
        __syncthreads();
#pragma unroll
        for (int ks = 0; ks < 2; ++ks) {
            const int cc = ks * 4 + (lane >> 4);
            bf16x8 fah[4], fal[4];
#pragma unroll
            for (int tm = 0; tm < 4; ++tm) {
                const int row = wm + tm * 16 + (lane & 15);
                fah[tm] = frag_ld(bufAh, row, cc);
                fal[tm] = frag_ld(bufAl, row, cc);
            }
#pragma unroll
            for (int tn = 0; tn < 4; ++tn) {
                const int rowb = wn + tn * 16 + (lane & 15);
                const bf16x8 fbh = frag_ld(bufBh, rowb, cc);
                const bf16x8 fbl = frag_ld(bufBl, rowb, cc);
#pragma unroll
                for (int tm = 0; tm < 4; ++tm) {
                    acc[tm][tn] = __builtin_amdgcn_mfma_f32_16x16x32_bf16(fah[tm], fbh, acc[tm][tn], 0, 0, 0);
                    acc[tm][tn] = __builtin_amdgcn_mfma_f32_16x16x32_bf16(fal[tm], fbh, acc[tm][tn], 0, 0, 0);
                    acc[tm][tn] = __builtin_amdgcn_mfma_f32_16x16x32_bf16(fah[tm], fbl, acc[tm][tn], 0, 0, 0);
                }
            }
        }
        __syncthreads();
    }

#pragma unroll
    for (int tn = 0; tn < 4; ++tn) {
        const int gn = j0 + wn + tn * 16 + (lane & 15);
        const float bvv = bias[gn];
        const int h = gn >> 6, d = gn & 63;
#pragma unroll
        for (int tm = 0; tm < 4; ++tm) {
#pragma unroll
            for (int reg = 0; reg < 4; ++reg) {
                const int gm = m0 + wm + tm * 16 + (lane >> 4) * 4 + reg;
                const int b = gm >> 11, l = gm & (LL - 1);
                Out[(((size_t)(b * HH + h)) * LL + l) * DD + d] = acc[tm][tn][reg] + bvv;
            }
        }
    }
}

// ---------------- K_C: measure + vmean1 in one launch -----------------------
// measure blocks XCD-swizzled: c = (orig%8)*256 + orig/8 (2048%8==0, bijective)
// -> each XCD owns 2 bh -> kp2 slices stay L2-resident per XCD.
__global__ __launch_bounds__(256) void measure_vmean_kernel(
    const float* __restrict__ qp2, const float* __restrict__ kp2,
    const float* __restrict__ vp2, const int* __restrict__ rnd,
    float* __restrict__ measure, float* __restrict__ partial) {
    __shared__ float pv[256];
    const int bx = blockIdx.x;
    const int t = threadIdx.x;
    if (bx < 2048) {
        const int c = (bx & 7) * 256 + (bx >> 3);
        const int lane = t & 63;
        const int wv = t >> 6;
        const int g = lane >> 4;
        const int dq = (lane & 15) * 4;
        const int bh = c >> 7;
        const int i = (c & 127) * 16 + wv * 4 + g;
        const float4 qv = *(const float4*)(qp2 + ((size_t)bh * LL + i) * DD + dq);
        const float* kbase = kp2 + (size_t)bh * LL * DD;
        const int* rp = rnd + i * NUMK;
        float mx = -INFINITY, sm = 0.f;
#pragma unroll 8
        for (int j = 0; j < NUMK; ++j) {
            const int row = rp[j];
            const float4 kv = *(const float4*)(kbase + (size_t)row * DD + dq);
            float p = kv.x * qv.x;
            p = fmaf(kv.y, qv.y, p); p = fmaf(kv.z, qv.z, p); p = fmaf(kv.w, qv.w, p);
            p += __shfl_xor(p, 1, 64);
            p += __shfl_xor(p, 2, 64);
            p += __shfl_xor(p, 4, 64);
            p += __shfl_xor(p, 8, 64);
            mx = fmaxf(mx, p);
            sm += p;
        }
        if ((lane & 15) == 0) measure[(size_t)bh * LL + i] = mx - sm * (1.0f / LL);
    } else {
        const int idx = bx - 2048;
        const int chunk = idx & 31;
        const int bh = idx >> 5;
        const int d = t & 63, g = t >> 6;
        const int l0 = chunk * 64;
        float acc = 0.f;
        for (int l = l0 + g; l < l0 + 64; l += 4)
            acc += vp2[((size_t)bh * LL + l) * DD + d];
        pv[t] = acc;
        __syncthreads();
        if (t < 64)
            partial[(size_t)idx * 64 + t] = pv[t] + pv[64 + t] + pv[128 + t] + pv[192 + t];
    }
}

// ---------------- K3: top-40 radix + vmean2 ---------------------------------
// Round-0 histogram via wave ballot aggregation; bin selection via
// single-wave shfl suffix-scan.
__global__ __launch_bounds__(256) void topk_kernel(const float* __restrict__ measure,
                                                   const float* __restrict__ partial,
                                                   int* __restrict__ q_idx,
                                                   int* __restrict__ sel_pos,
                                                   float* __restrict__ v_mean) {
    __shared__ unsigned int keys[LL];      // 8 KB
    __shared__ int hist[256];
    __shared__ unsigned int prefix_sh;
    __shared__ int need_sh;
    __shared__ unsigned int cval[256];
    __shared__ int cidx[256];
    __shared__ int cnt;
    const int t = threadIdx.x;
    const int lane = t & 63;
    const int bh = blockIdx.x;
    for (int i = t; i < LL; i += 256) {
        const float f = measure[(size_t)bh * LL + i];
        unsigned int u = __float_as_uint(f);
        keys[i] = (u & 0x80000000u) ? ~u : (u | 0x80000000u);
        sel_pos[(size_t)bh * LL + i] = -1;
    }
    // folded vmean2: independent of topk state
    if (t < 64) {
        float s = 0.f;
        for (int c = 0; c < 32; ++c)
            s += partial[((size_t)bh * 32 + c) * 64 + t];
        v_mean[bh * 64 + t] = s * (1.0f / LL);
    }
    if (t == 0) { prefix_sh = 0u; need_sh = NUMQ; cnt = 0; }
    __syncthreads();

    for (int round = 0; round < 4; ++round) {
        const int shift = 24 - round * 8;
        hist[t] = 0;
        __syncthreads();
        const unsigned int pref = prefix_sh;
        if (round == 0) {
            // leader-election aggregation (all lanes active; LL % 256 == 0)
            for (int i = t; i < LL; i += 256) {
                const int b = (int)(keys[i] >> 24);
                unsigned long long rem = ~0ull;
                while (rem) {
                    const int leader = __ffsll((long long)rem) - 1;
                    const int b0 = __shfl(b, leader, 64);
                    const unsigned long long same = __ballot(b == b0) & rem;
                    if (lane == leader) atomicAdd(&hist[b0], (int)__popcll(same));
                    rem &= ~same;
                }
            }
        } else {
            const unsigned int mask = 0xFFFFFFFFu << (shift + 8);
            for (int i = t; i < LL; i += 256) {
                const unsigned int key = keys[i];
                if ((key & mask) == pref)
                    atomicAdd(&hist[(key >> shift) & 0xFF], 1);
            }
        }
        __syncthreads();
        // single-wave suffix-scan bin selection (t < 64 -> wave 0)
        if (t < 64) {
            const int b0 = hist[4 * t + 0], b1 = hist[4 * t + 1];
            const int b2 = hist[4 * t + 2], b3 = hist[4 * t + 3];
            const int loc = b0 + b1 + b2 + b3;
            int suf = loc;
#pragma unroll
            for (int off = 1; off < 64; off <<= 1) {
                const int other = __shfl_down(suf, off, 64);
                if (lane + off < 64) suf += other;
            }
            // suf = suffix(4t) inclusive
            const int need = need_sh;
            int s[5];
            s[0] = suf;
            s[1] = suf - b0;
            s[2] = suf - b0 - b1;
            s[3] = suf - b0 - b1 - b2;
            s[4] = suf - loc;
#pragma unroll
            for (int kk = 0; kk < 4; ++kk) {
                if (s[kk] >= need && s[kk + 1] < need) {
                    need_sh = need - s[kk + 1];
                    prefix_sh = pref | ((unsigned int)(4 * t + kk) << shift);
                }
            }
        }
        __syncthreads();
    }
    const unsigned int K40 = prefix_sh;

    for (int i = t; i < LL; i += 256) {
        if (keys[i] >= K40) {
            int p = atomicAdd(&cnt, 1);
            if (p < 256) { cval[p] = keys[i]; cidx[p] = i; }
        }
    }
    __syncthreads();
    int M = cnt; if (M > 256) M = 256;
    for (int i = t; i < M; i += 256) {
        const unsigned int ki = cval[i];
        const int ii = cidx[i];
        int r = 0;
        for (int j = 0; j < M; ++j) {
            const unsigned int kj = cval[j];
            r += (kj > ki || (kj == ki && cidx[j] < ii)) ? 1 : 0;
        }
        if (r < NUMQ) {
            q_idx[bh * NUMQ + r] = ii;
            sel_pos[(size_t)bh * LL + ii] = r;
        }
    }
}

// ---------------- K4a: attn partial — all 40 queries per block --------------
// One block per (bh, 128-key segment). K staged, barrier, THEN V-stage issued
// so it flies under QK^T (T14 issue-early); V drained by the pre-PV barrier.
__global__ __launch_bounds__(256) void attn_part_kernel(
    const float* __restrict__ qp2, const float* __restrict__ kp2,
    const float* __restrict__ vp2, const int* __restrict__ q_idx,
    float* __restrict__ attn_out, float* __restrict__ part_m,
    float* __restrict__ part_s, float* __restrict__ part_pv) {
    __shared__ __align__(16) float Qs[NUMQ][68];        // ~10.9 KB, q * 0.125
    __shared__ __align__(16) float Ks[LSEG * 64];       // 32 KB, XOR-swizzled
    __shared__ __align__(16) float Vs[LSEG * 64];       // 32 KB, XOR-swizzled
    __shared__ __align__(16) float Ss[NUMQ][136];       // ~21.8 KB, exp'd P
    const int t = threadIdx.x;
    const int lane = t & 63, w = t >> 6;
    // flat 256-block grid; c = (orig%8)*32 + orig/8 (256%8==0, bijective)
    const int orig = blockIdx.x;
    const int cc_ = (orig & 7) * 32 + (orig >> 3);
    const int bh = cc_ >> 4;
    const int ls = cc_ & 15;
    const int l0 = ls * LSEG;

    // ---- load Q (scaled by D^-1/2 = 0.125) ----
    for (int idx = t; idx < NUMQ * 16; idx += 256) {
        const int r = idx >> 4, c4 = idx & 15;
        const int qi = q_idx[bh * NUMQ + r];
        float4 v = *(const float4*)(qp2 + ((size_t)bh * LL + qi) * DD + c4 * 4);
        Qs[r][c4 * 4 + 0] = v.x * 0.125f;
        Qs[r][c4 * 4 + 1] = v.y * 0.125f;
        Qs[r][c4 * 4 + 2] = v.z * 0.125f;
        Qs[r][c4 * 4 + 3] = v.w * 0.125f;
    }

    // ---- stage K segment ----
    const float* kseg = kp2 + ((size_t)bh * LL + l0) * DD;
    const float* vseg = vp2 + ((size_t)bh * LL + l0) * DD;
#pragma unroll
    for (int i = 0; i < 8; ++i) {
        const int r0 = (w * 8 + i) * 4;                 // wave-uniform
        const int r = r0 + (lane >> 4);
        const int cg = (lane & 15) ^ (r & 15);
        __builtin_amdgcn_global_load_lds(
            (const __attribute__((address_space(1))) unsigned int*)(kseg + (size_t)r * DD + cg * 4),
            (__attribute__((address_space(3))) unsigned int*)(Ks + r0 * 64), 16, 0, 0);
    }
    __syncthreads();   // Q writes + K gloads drained

    // ---- issue V staging now: flies under QK^T, drained by next barrier ----
#pragma unroll
    for (int i = 0; i < 8; ++i) {
        const int r0 = (w * 8 + i) * 4;                 // wave-uniform
        const int r = r0 + (lane >> 4);
        const int cg = (lane & 15) ^ (r & 15);
        __builtin_amdgcn_global_load_lds(
            (const __attribute__((address_space(1))) unsigned int*)(vseg + (size_t)r * DD + cg * 4),
            (__attribute__((address_space(3))) unsigned int*)(Vs + r0 * 64), 16, 0, 0);
    }

    // ---- QK^T: acc[5][4] ----
    const int qt = t >> 5;          // 0..7  (32-thread group per q-residue)
    const int jt = t & 31;          // 0..31
    float acc[5][4];
#pragma unroll
    for (int i = 0; i < 5; ++i)
#pragma unroll
        for (int jj = 0; jj < 4; ++jj) acc[i][jj] = 0.f;

    for (int c4 = 0; c4 < 16; ++c4) {
        float4 q4[5];
#pragma unroll
        for (int i = 0; i < 5; ++i)
            q4[i] = *(const float4*)&Qs[qt + 8 * i][c4 * 4];    // broadcast
#pragma unroll
        for (int jj = 0; jj < 4; ++jj) {
            const int r = jt + 32 * jj;
            const float4 k4 = *(const float4*)&Ks[r * 64 + ((c4 ^ (r & 15)) * 4)];
#pragma unroll
            for (int i = 0; i < 5; ++i) {
                acc[i][jj] = fmaf(q4[i].x, k4.x, acc[i][jj]);
                acc[i][jj] = fmaf(q4[i].y, k4.y, acc[i][jj]);
                acc[i][jj] = fmaf(q4[i].z, k4.z, acc[i][jj]);
                acc[i][jj] = fmaf(q4[i].w, k4.w, acc[i][jj]);
            }
        }
    }

    // ---- per-row partial softmax (max & sum over this 128-seg) ----
#pragma unroll
    for (int i = 0; i < 5; ++i) {
        const int r = qt + 8 * i;
        float m = fmaxf(fmaxf(acc[i][0], acc[i][1]), fmaxf(acc[i][2], acc[i][3]));
        m = fmaxf(m, __shfl_xor(m, 16, 64));
        m = fmaxf(m, __shfl_xor(m, 8, 64));
        m = fmaxf(m, __shfl_xor(m, 4, 64));
        m = fmaxf(m, __shfl_xor(m, 2, 64));
        m = fmaxf(m, __shfl_xor(m, 1, 64));
        float p0 = __expf(acc[i][0] - m), p1 = __expf(acc[i][1] - m);
        float p2 = __expf(acc[i][2] - m), p3 = __expf(acc[i][3] - m);
        Ss[r][jt]      = p0;
        Ss[r][jt + 32] = p1;
        Ss[r][jt + 64] = p2;
        Ss[r][jt + 96] = p3;
        float s = p0 + p1 + p2 + p3;
        s += __shfl_xor(s, 16, 64);
        s += __shfl_xor(s, 8, 64);
        s += __shfl_xor(s, 4, 64);
        s += __shfl_xor(s, 2, 64);
        s += __shfl_xor(s, 1, 64);
        if (jt == 0) {
            const int row = bh * NUMQ + r;
            part_m[row * NLS + ls] = m;
            part_s[row * NLS + ls] = s;
        }
    }
    __syncthreads();   // drains V gloads + Ss writes

    // ---- coalesced write of unnormalized P to attn_out ----
    for (int idx = t; idx < NUMQ * 32; idx += 256) {
        const int r = idx >> 5, c4 = idx & 31;
        const float4 v = *(const float4*)&Ss[r][c4 * 4];
        *(float4*)(attn_out + (size_t)(bh * NUMQ + r) * LL + l0 + c4 * 4) = v;
    }

    // ---- PV: thread tile 5q x 2d; P read as float4 per 4-j ----
    const int dt = t & 31;
    float o[5][2];
#pragma unroll
    for (int i = 0; i < 5; ++i) { o[i][0] = 0.f; o[i][1] = 0.f; }
#pragma unroll 2
    for (int j0_ = 0; j0_ < LSEG; j0_ += 4) {
        float4 p4[5];
#pragma unroll
        for (int i = 0; i < 5; ++i)
            p4[i] = *(const float4*)&Ss[qt + 8 * i][j0_];       // broadcast b128
#pragma unroll
        for (int jj = 0; jj < 4; ++jj) {
            const int j = j0_ + jj;
            const int pg = (dt >> 1) ^ (j & 15);
            const float* vr = &Vs[j * 64 + pg * 4 + (dt & 1) * 2];
            const float v0 = vr[0], v1 = vr[1];
#pragma unroll
            for (int i = 0; i < 5; ++i) {
                const float p = ((const float*)&p4[i])[jj];     // jj compile-time
                o[i][0] = fmaf(p, v0, o[i][0]);
                o[i][1] = fmaf(p, v1, o[i][1]);
            }
        }
    }
#pragma unroll
    for (int i = 0; i < 5; ++i) {
        const int row = bh * NUMQ + qt + 8 * i;
        float* pp = part_pv + ((size_t)row * NLS + ls) * DD + dt * 2;
        pp[0] = o[i][0];
        pp[1] = o[i][1];
    }
}

// ---------------- K_F: final (token LN) + attn rescale, one launch ----------
__global__ __launch_bounds__(512) void final_all_kernel(
    const float* __restrict__ q_in, const int* __restrict__ sel_pos,
    const float* __restrict__ part_m, const float* __restrict__ part_s,
    const float* __restrict__ part_pv, const float* __restrict__ v_mean,
    const float* __restrict__ gamma, const float* __restrict__ beta,
    float* __restrict__ attn_out, float* __restrict__ yout) {
    __shared__ float wred[8];
    const int bx = blockIdx.x;
    const int j = threadIdx.x;
    if (bx >= BB * LL) {
        // ---- attn_out row rescale: 512 threads x one float4 = 2048 cols ----
        const int row = bx - BB * LL;        // bh*NUMQ + q
        float M = -INFINITY;
#pragma unroll
        for (int i = 0; i < NLS; ++i) M = fmaxf(M, part_m[row * NLS + i]);
        float T = 0.f;
#pragma unroll
        for (int i = 0; i < NLS; ++i)
            T += part_s[row * NLS + i] * __expf(part_m[row * NLS + i] - M);
        const float inv = 1.0f / T;
        const int s0 = j >> 5;               // col 4j -> segment (4j)>>7
        const float g = __expf(part_m[row * NLS + s0] - M) * inv;
        float* arow = attn_out + (size_t)row * LL;
        float4 v = *(const float4*)&arow[4 * j];
        v.x *= g; v.y *= g; v.z *= g; v.w *= g;
        *(float4*)&arow[4 * j] = v;
        return;
    }
    const int lane = j & 63, wv = j >> 6;
    const int tok = bx;                      // b*L + l
    const int b = tok >> 11;
    const int l = tok & (LL - 1);
    const int h = wv, d = lane;
    const int bh = b * HH + h;
    const int p = sel_pos[(size_t)bh * LL + l];
    float val;
    if (p >= 0) {
        const int row = bh * NUMQ + p;
        float M = -INFINITY;
#pragma unroll
        for (int i = 0; i < NLS; ++i) M = fmaxf(M, part_m[row * NLS + i]);
        float T = 0.f, s = 0.f;
#pragma unroll
        for (int i = 0; i < NLS; ++i) {
            const float e = __expf(part_m[row * NLS + i] - M);
            T += part_s[row * NLS + i] * e;
            s += part_pv[((size_t)row * NLS + i) * DD + d] * e;
        }
        val = s * (1.0f / T);
    } else {
        val = v_mean[bh * DD + d];
    }
    float y = val + q_in[(size_t)tok * DMM + j];
    float s = y;
#pragma unroll
    for (int off = 32; off > 0; off >>= 1) s += __shfl_xor(s, off, 64);
    if (lane == 0) wred[wv] = s;
    __syncthreads();
    float tot = 0.f;
#pragma unroll
    for (int u = 0; u < 8; ++u) tot += wred[u];
    float mu = tot * (1.0f / DMM);
    __syncthreads();
    float dv = y - mu;
    float s2 = dv * dv;
#pragma unroll
    for (int off = 32; off > 0; off >>= 1) s2 += __shfl_xor(s2, off, 64);
    if (lane == 0) wred[wv] = s2;
    __syncthreads();
    float tot2 = 0.f;
#pragma unroll
    for (int u = 0; u < 8; ++u) tot2 += wred[u];
    float var = tot2 * (1.0f / DMM);
    float yn = dv * rsqrtf(var + LNEPS) * gamma[j] + beta[j];
    yout[(size_t)tok * DMM + j] = yn;
}

extern "C" void kernel_launch(void* const* d_in, const int* in_sizes, int n_in,
                              void* d_out, int out_size, void* d_ws, size_t ws_size,
                              hipStream_t stream) {
    const float* q     = (const float*)d_in[0];
    const float* k     = (const float*)d_in[1];
    const float* v     = (const float*)d_in[2];
    const float* Wq    = (const float*)d_in[3];
    const float* bq    = (const float*)d_in[4];
    const float* Wk    = (const float*)d_in[5];
    const float* bk    = (const float*)d_in[6];
    const float* Wv    = (const float*)d_in[7];
    const float* bv    = (const float*)d_in[8];
    const float* gamma = (const float*)d_in[9];
    const float* beta  = (const float*)d_in[10];
    const int*   rnd   = (const int*)d_in[11];

    float* ws = (float*)d_ws;
    const size_t proj_sz = (size_t)BB * HH * LL * DD;      // = B*L*DM elements
    float* qp2     = ws;
    float* kp2     = qp2 + proj_sz;
    float* vp2     = kp2 + proj_sz;
    float* measure = vp2 + proj_sz;                        // B*H*L
    float* out_sel = measure + (size_t)BB * HH * LL;       // (unused slot)
    float* v_mean  = out_sel + (size_t)BB * HH * NUMQ * DD;// B*H*D
    float* partial = v_mean + (size_t)BB * HH * DD;        // B*H*32*64
    float* part_m  = partial + (size_t)BB * HH * 32 * 64;  // 640*NLS
    float* part_s  = part_m + (size_t)BB * HH * NUMQ * NLS;
    float* part_pv = part_s + (size_t)BB * HH * NUMQ * NLS;// 640*NLS*64
    int*   q_idx   = (int*)(part_pv + (size_t)BB * HH * NUMQ * NLS * DD);
    int*   sel_pos = q_idx + BB * HH * NUMQ;               // B*H*L
    ushort_t* Xh  = (ushort_t*)(sel_pos + BB * HH * LL);
    ushort_t* Xl  = Xh + 3 * proj_sz;
    ushort_t* Wht = Xl + 3 * proj_sz;
    ushort_t* Wlt = Wht + 3 * (size_t)DMM * DMM;

    float* yn_out   = (float*)d_out;
    float* attn_out = yn_out + (size_t)BB * LL * DMM;

    convert_all_kernel<<<3072 + 192, 256, 0, stream>>>(q, k, v, Wq, Wk, Wv, Xh, Xl, Wht, Wlt);
    proj_mfma_kernel<<<dim3(3 * (BB * LL / 128) * (DMM / 128), 1, 1), 256, 0, stream>>>(
        Xh, Xl, Wht, Wlt, bq, bk, bv, qp2, kp2, vp2);
    measure_vmean_kernel<<<2048 + 512, 256, 0, stream>>>(qp2, kp2, vp2, rnd, measure, partial);
    topk_kernel<<<BB * HH, 256, 0, stream>>>(measure, partial, q_idx, sel_pos, v_mean);
    attn_part_kernel<<<BB * HH * NLS, 256, 0, stream>>>(
        qp2, kp2, vp2, q_idx, attn_out, part_m, part_s, part_pv);
    final_all_kernel<<<BB * LL + BB * HH * NUMQ, 512, 0, stream>>>(
        q, sel_pos, part_m, part_s, part_pv, v_mean, gamma, beta, attn_out, yn_out);
}